// Round 5
// baseline (27.244 us; speedup 1.0000x reference)
//
#include <hip/hip_runtime.h>

// PositionalEmbedding: out[p][e] = (fmod(p*div[e], 2) == 0) ? sin(p*div[e]) : cos(p*div[e])
// P = 32768 positions, E = 1024 embedding dims. Output fp32, write-only ~134 MB.
//
// HW v_sin_f32 (input in REVOLUTIONS, v_fract-reduced); cos folded via +0.25 rev.
// Parity via fract(pe*0.5)==0  (exact: pe*0.5 is pow2-scale, pe < 2^23).
// Nontemporal 16B stores (native ext_vector type — HIP float4 class is rejected
// by __builtin_nontemporal_store).

#define PE_E 1024
#define PE_P 32768

typedef float f32x4 __attribute__((ext_vector_type(4)));

__device__ __forceinline__ float sincos_sel(float pe) {
    // fmod(pe,2)==0  <=>  pe/2 is an integer  <=>  fract(pe*0.5)==0 (all exact)
    float h = pe * 0.5f;
    float even = __builtin_amdgcn_fractf(h);
    const float INV_2PI = 0.15915494309189535f;
    float off = (even == 0.0f) ? 0.0f : 0.25f;  // +0.25 rev == +pi/2: sin -> cos
    float r = __builtin_fmaf(pe, INV_2PI, off);
    float fr = __builtin_amdgcn_fractf(r);       // reduce to [0,1) for v_sin_f32
    return __builtin_amdgcn_sinf(fr);            // v_sin_f32 (revolutions)
}

__global__ __launch_bounds__(256) void PositionalEmbedding_75685913690611_kernel(
    const float* __restrict__ div, float* __restrict__ out) {
    // t in [0, P/4 * E/4): cg = column-group, rowBase = 4 consecutive rows
    int t = blockIdx.x * blockDim.x + threadIdx.x;
    int cg      = t & 255;          // E/4 = 256 column groups
    int rowBase = (t >> 8) << 2;    // 4 rows per thread

    f32x4 d = *reinterpret_cast<const f32x4*>(div + (cg << 2));
    f32x4* outv = reinterpret_cast<f32x4*>(out);

    #pragma unroll
    for (int i = 0; i < 4; ++i) {
        float p = (float)(rowBase + i);   // exact in fp32 (p < 2^15)
        f32x4 o;
        o.x = sincos_sel(p * d.x);
        o.y = sincos_sel(p * d.y);
        o.z = sincos_sel(p * d.z);
        o.w = sincos_sel(p * d.w);
        __builtin_nontemporal_store(o, &outv[(rowBase + i) * 256 + cg]);
    }
}

extern "C" void kernel_launch(void* const* d_in, const int* in_sizes, int n_in,
                              void* d_out, int out_size, void* d_ws, size_t ws_size,
                              hipStream_t stream) {
    const float* div = (const float*)d_in[1];  // d_in[0] = x (shape-only)
    float* out = (float*)d_out;                // out_size = 32768*1024

    int threads_total = (PE_P / 4) * (PE_E / 4);  // 2,097,152
    int block = 256;
    int grid = threads_total / block;             // 8192 blocks
    PositionalEmbedding_75685913690611_kernel<<<grid, block, 0, stream>>>(div, out);
}

// Round 6
// 26.474 us; speedup vs baseline: 1.0291x; 1.0291x over previous
//
#include <hip/hip_runtime.h>

// PositionalEmbedding: out[p][e] = (fmod(p*div[e], 2) == 0) ? sin(p*div[e]) : cos(p*div[e])
// P = 32768 positions, E = 1024 embedding dims. Output fp32, write-only ~134 MB.
//
// HW v_sin_f32 (input in REVOLUTIONS, v_fract-reduced); cos folded via +0.25 rev.
// Parity via fract(pe*0.5)==0  (exact: pe*0.5 is pow2-scale, pe < 2^23).
// Persistent-ish grid: 2048 WGs (8/CU), each thread owns 16 rows x 1 col-group
// -> 4x fewer workgroups, ramp/pipeline-fill amortized over 16 stores/thread.
// Plain (cached) float4 stores — nontemporal regressed in round 5.

#define PE_E 1024
#define PE_P 32768

__device__ __forceinline__ float sincos_sel(float pe) {
    // fmod(pe,2)==0  <=>  pe/2 integral  <=>  fract(pe*0.5)==0 (exact, pe < 2^23)
    float even = __builtin_amdgcn_fractf(pe * 0.5f);
    const float INV_2PI = 0.15915494309189535f;
    float off = (even == 0.0f) ? 0.0f : 0.25f;  // +0.25 rev == +pi/2: sin -> cos
    float r = __builtin_fmaf(pe, INV_2PI, off);
    float fr = __builtin_amdgcn_fractf(r);       // reduce to [0,1) for v_sin_f32
    return __builtin_amdgcn_sinf(fr);            // v_sin_f32 (revolutions)
}

__global__ __launch_bounds__(256) void PositionalEmbedding_75685913690611_kernel(
    const float* __restrict__ div, float* __restrict__ out) {
    // tid -> column-group (cg = 0..255 within the block); block -> 16-row band.
    int cg      = threadIdx.x;           // E/4 = 256 col groups = block width
    int rowBase = blockIdx.x << 4;       // 16 rows per block band

    float4 d = *reinterpret_cast<const float4*>(div + (cg << 2));
    float4* outv = reinterpret_cast<float4*>(out);

    #pragma unroll 4
    for (int i = 0; i < 16; ++i) {
        float p = (float)(rowBase + i);  // exact in fp32 (p < 2^15)
        float4 o;
        o.x = sincos_sel(p * d.x);
        o.y = sincos_sel(p * d.y);
        o.z = sincos_sel(p * d.z);
        o.w = sincos_sel(p * d.w);
        outv[(rowBase + i) * 256 + cg] = o;   // wave-coalesced 1KB/wave/iter
    }
}

extern "C" void kernel_launch(void* const* d_in, const int* in_sizes, int n_in,
                              void* d_out, int out_size, void* d_ws, size_t ws_size,
                              hipStream_t stream) {
    const float* div = (const float*)d_in[1];  // d_in[0] = x (shape-only)
    float* out = (float*)d_out;                // out_size = 32768*1024

    int block = 256;                 // one col-group per thread
    int grid  = PE_P / 16;           // 2048 blocks, 16-row band each
    PositionalEmbedding_75685913690611_kernel<<<grid, block, 0, stream>>>(div, out);
}

// Round 7
// 25.871 us; speedup vs baseline: 1.0530x; 1.0233x over previous
//
#include <hip/hip_runtime.h>

// PositionalEmbedding: out[p][e] = (fmod(p*div[e], 2) == 0) ? sin(p*div[e]) : cos(p*div[e])
// P = 32768 positions, E = 1024 embedding dims. Output fp32, write-only ~134 MB.
//
// Best-of-plateau configuration (rounds 2-6 all land 25.7-27.2 us):
//  - HW v_sin_f32 (input in REVOLUTIONS, v_fract-reduced); cos via +0.25 rev.
//  - Parity via fract(pe*0.5)==0 (exact: pow2 scale, pe < 2^23) == fmodf(pe,2)==0.
//  - 4 rows x 1 col-group per thread, 8192 WGs, plain cached float4 stores
//    (nontemporal regressed: 27.2 us; persistent 16-row bands: 26.5 us).

#define PE_E 1024
#define PE_P 32768

__device__ __forceinline__ float sincos_sel(float pe) {
    float even = __builtin_amdgcn_fractf(pe * 0.5f);
    const float INV_2PI = 0.15915494309189535f;
    float off = (even == 0.0f) ? 0.0f : 0.25f;  // +0.25 rev == +pi/2: sin -> cos
    float r = __builtin_fmaf(pe, INV_2PI, off);
    float fr = __builtin_amdgcn_fractf(r);       // reduce to [0,1) for v_sin_f32
    return __builtin_amdgcn_sinf(fr);            // v_sin_f32 (revolutions)
}

__global__ __launch_bounds__(256) void PositionalEmbedding_75685913690611_kernel(
    const float* __restrict__ div, float* __restrict__ out) {
    int t = blockIdx.x * blockDim.x + threadIdx.x;
    int cg      = t & 255;          // E/4 = 256 column groups
    int rowBase = (t >> 8) << 2;    // 4 rows per thread

    float4 d = *reinterpret_cast<const float4*>(div + (cg << 2));
    float4* outv = reinterpret_cast<float4*>(out);

    #pragma unroll
    for (int i = 0; i < 4; ++i) {
        float p = (float)(rowBase + i);   // exact in fp32 (p < 2^15)
        float4 o;
        o.x = sincos_sel(p * d.x);
        o.y = sincos_sel(p * d.y);
        o.z = sincos_sel(p * d.z);
        o.w = sincos_sel(p * d.w);
        outv[(rowBase + i) * 256 + cg] = o;   // wave-coalesced
    }
}

extern "C" void kernel_launch(void* const* d_in, const int* in_sizes, int n_in,
                              void* d_out, int out_size, void* d_ws, size_t ws_size,
                              hipStream_t stream) {
    const float* div = (const float*)d_in[1];  // d_in[0] = x (shape-only)
    float* out = (float*)d_out;                // out_size = 32768*1024

    int threads_total = (PE_P / 4) * (PE_E / 4);  // 2,097,152
    int block = 256;
    int grid = threads_total / block;             // 8192 blocks
    PositionalEmbedding_75685913690611_kernel<<<grid, block, 0, stream>>>(div, out);
}